// Round 1
// baseline (128.196 us; speedup 1.0000x reference)
//
#include <hip/hip_runtime.h>

#define P 10
#define D 1024
#define NROWS 16384

// ---------------------------------------------------------------------------
// Kernel A: build per-(stage, position) coefficient table.
// coef4[j*D + k] = (u_re, u_im, v_re, v_im) at stage j, column k.
// Derivation from the reference's interleave + IDX_UV gather:
//   i = IDX_UV[j][k]  has  i&1 = bit j of k  (b),  i>>1 = k with bit j deleted (m).
//   u_re raw = interleave(-s1*s2, s1^2)   -> b ?  s1*s1 : -s1*s2
//   v_re raw = interleave(-c1*s1, -c1*s2) -> b ? -c1*s2 : -c1*s1
//   u_im raw = interleave( s1*c2, -c1*s1) -> b ? -c1*s1 :  s1*c2
//   v_im raw = interleave( c1^2,  c1*c2)  -> b ?  c1*c2 :  c1*c1
// The final psi rotation (applied at output position k) is folded into the
// stage-9 coefficients: (u,v) *= e^{i*psi[k]}.
// ---------------------------------------------------------------------------
__global__ void coef_kernel(const float* __restrict__ theta,
                            const float* __restrict__ phi,
                            const float* __restrict__ psi,
                            float4* __restrict__ coef) {
    int idx = blockIdx.x * blockDim.x + threadIdx.x;
    if (idx >= P * D) return;
    int j = idx >> 10;          // stage
    int k = idx & (D - 1);      // column
    int b = (k >> j) & 1;
    unsigned lowmask = (1u << j) - 1u;
    unsigned m = ((unsigned)k & lowmask) | (((unsigned)k >> 1) & ~lowmask); // delete bit j
    float th = theta[j * (D / 2) + m];
    float ph = phi[j * (D / 2) + m];
    float h = th * 0.5f;
    float s1 = sinf(h), c1 = cosf(h);
    float s2 = sinf(h + ph), c2 = cosf(h + ph);
    float ur, ui, vr, vi;
    if (b) { ur =  s1 * s1; vr = -c1 * s2; ui = -c1 * s1; vi = c1 * c2; }
    else   { ur = -s1 * s2; vr = -c1 * s1; ui =  s1 * c2; vi = c1 * c1; }
    if (j == P - 1) {
        float ps = psi[k];
        float cp = cosf(ps), sp = sinf(ps);
        float ur2 = cp * ur - sp * ui, ui2 = sp * ur + cp * ui;
        float vr2 = cp * vr - sp * vi, vi2 = sp * vr + cp * vi;
        ur = ur2; ui = ui2; vr = vr2; vi = vi2;
    }
    coef[idx] = make_float4(ur, ui, vr, vi);
}

// ---------------------------------------------------------------------------
// Kernel B: butterfly network. One wave (64 lanes) processes 2 rows.
// Column mapping: k = e*64 + lane, e in [0,16).
//   stages 0..5 : partner differs in a lane bit  -> __shfl_xor (in-register)
//   stages 6..9 : partner differs in an e bit    -> pure register permutation
// Coefficient float4 loads are coalesced (consecutive lanes -> consecutive k)
// and reused across the 2 rows held per thread.
// ---------------------------------------------------------------------------
template <int J, int PM>
__device__ __forceinline__ void stage_intra(float (&ra)[16], float (&ia)[16],
                                            float (&rb)[16], float (&ib)[16],
                                            const float4* __restrict__ coef, int lane) {
    const float4* cj = coef + J * D + lane;
#pragma unroll
    for (int e0 = 0; e0 < 16; ++e0) {
        if (e0 & PM) continue;
        const int e1 = e0 | PM;
        float4 c0 = cj[e0 * 64];
        float4 c1 = cj[e1 * 64];
        float ar0 = ra[e0], ai0 = ia[e0], ar1 = ra[e1], ai1 = ia[e1];
        float br0 = rb[e0], bi0 = ib[e0], br1 = rb[e1], bi1 = ib[e1];
        ra[e0] = c0.x * ar0 - c0.y * ai0 + c0.z * ar1 - c0.w * ai1;
        ia[e0] = c0.x * ai0 + c0.y * ar0 + c0.z * ai1 + c0.w * ar1;
        ra[e1] = c1.x * ar1 - c1.y * ai1 + c1.z * ar0 - c1.w * ai0;
        ia[e1] = c1.x * ai1 + c1.y * ar1 + c1.z * ai0 + c1.w * ar0;
        rb[e0] = c0.x * br0 - c0.y * bi0 + c0.z * br1 - c0.w * bi1;
        ib[e0] = c0.x * bi0 + c0.y * br0 + c0.z * bi1 + c0.w * br1;
        rb[e1] = c1.x * br1 - c1.y * bi1 + c1.z * br0 - c1.w * bi0;
        ib[e1] = c1.x * bi1 + c1.y * br1 + c1.z * bi0 + c1.w * br0;
    }
}

__global__ __launch_bounds__(256) void fft_kernel(const float* __restrict__ X,
                                                  const float4* __restrict__ coef,
                                                  float* __restrict__ out) {
    const int lane = threadIdx.x & 63;
    const int wave = threadIdx.x >> 6;
    const long rowbase = (long)blockIdx.x * 8 + (long)wave * 2;
    const float* x0 = X + rowbase * 2048;
    const float* x1 = x0 + 2048;

    float ra[16], ia[16], rb[16], ib[16];
#pragma unroll
    for (int e = 0; e < 16; ++e) {
        int o = e * 64 + lane;
        ra[e] = x0[o];
        ia[e] = x0[o + 1024];
        rb[e] = x1[o];
        ib[e] = x1[o + 1024];
    }

    // stages 0..5: cross-lane via shuffle
    for (int j = 0; j < 6; ++j) {
        const int mask = 1 << j;
        const float4* cj = coef + j * D + lane;
#pragma unroll
        for (int e = 0; e < 16; ++e) {
            float4 c = cj[e * 64];
            float sra = __shfl_xor(ra[e], mask);
            float sia = __shfl_xor(ia[e], mask);
            float srb = __shfl_xor(rb[e], mask);
            float sib = __shfl_xor(ib[e], mask);
            float nra = c.x * ra[e] - c.y * ia[e] + c.z * sra - c.w * sia;
            float nia = c.x * ia[e] + c.y * ra[e] + c.z * sia + c.w * sra;
            float nrb = c.x * rb[e] - c.y * ib[e] + c.z * srb - c.w * sib;
            float nib = c.x * ib[e] + c.y * rb[e] + c.z * sib + c.w * srb;
            ra[e] = nra; ia[e] = nia; rb[e] = nrb; ib[e] = nib;
        }
    }

    // stages 6..9: intra-thread on e bits (psi folded into stage 9 coefs)
    stage_intra<6, 1>(ra, ia, rb, ib, coef, lane);
    stage_intra<7, 2>(ra, ia, rb, ib, coef, lane);
    stage_intra<8, 4>(ra, ia, rb, ib, coef, lane);
    stage_intra<9, 8>(ra, ia, rb, ib, coef, lane);

    float* o0 = out + rowbase * 2048;
    float* o1 = o0 + 2048;
#pragma unroll
    for (int e = 0; e < 16; ++e) {
        int o = e * 64 + lane;
        o0[o] = ra[e];
        o0[o + 1024] = ia[e];
        o1[o] = rb[e];
        o1[o + 1024] = ib[e];
    }
}

extern "C" void kernel_launch(void* const* d_in, const int* in_sizes, int n_in,
                              void* d_out, int out_size, void* d_ws, size_t ws_size,
                              hipStream_t stream) {
    const float* X     = (const float*)d_in[0];
    const float* theta = (const float*)d_in[1];
    const float* phi   = (const float*)d_in[2];
    const float* psi   = (const float*)d_in[3];
    float4* coef = (float4*)d_ws;   // P*D*sizeof(float4) = 160 KB

    coef_kernel<<<(P * D + 255) / 256, 256, 0, stream>>>(theta, phi, psi, coef);
    fft_kernel<<<NROWS / 8, 256, 0, stream>>>(X, coef, (float*)d_out);
}